// Round 6
// 187.460 us; speedup vs baseline: 1.0078x; 1.0078x over previous
//
#include <hip/hip_runtime.h>
#include <hip/hip_bf16.h>

#define B_  8
#define C_  256
#define CI_ 64
#define N_  4096
#define KSPLIT 4
#define KTILES (N_ / 64 / KSPLIT)   // 16 key-tiles per split-slice

typedef short short8  __attribute__((ext_vector_type(8)));
typedef short sh4     __attribute__((ext_vector_type(4)));
typedef float floatx4 __attribute__((ext_vector_type(4)));

#define LOG2E 1.4426950408889634f

__device__ __forceinline__ unsigned short f2bf(float f) {
    unsigned u = __builtin_bit_cast(unsigned, f);
    u += 0x7FFFu + ((u >> 16) & 1u);   // round-to-nearest-even
    return (unsigned short)(u >> 16);
}
__device__ __forceinline__ float bf2f(unsigned short h) {
    unsigned u = ((unsigned)h) << 16;
    return __builtin_bit_cast(float, u);
}

// packed f32x2 -> bf16x2
__device__ __forceinline__ unsigned pk2(float a, float b) {
#if __has_builtin(__builtin_amdgcn_cvt_pk_bf16_f32)
    auto r = __builtin_amdgcn_cvt_pk_bf16_f32(a, b);
    return __builtin_bit_cast(unsigned, r);
#else
    return (unsigned)f2bf(a) | ((unsigned)f2bf(b) << 16);
#endif
}

__device__ __forceinline__ floatx4 mfma32(short8 a, short8 b, floatx4 c) {
    return __builtin_amdgcn_mfma_f32_16x16x32_bf16(a, b, c, 0, 0, 0);
}
__device__ __forceinline__ floatx4 mfma16(sh4 a, sh4 b, floatx4 c) {
#if __has_builtin(__builtin_amdgcn_mfma_f32_16x16x16bf16_1k)
    return __builtin_amdgcn_mfma_f32_16x16x16bf16_1k(a, b, c, 0, 0, 0);
#else
    floatx4 d;
    asm("v_mfma_f32_16x16x16_bf16 %0, %1, %2, %3" : "=v"(d) : "v"(a), "v"(b), "v"(c));
    return d;
#endif
}

// ---------------------------------------------------------------------------
// Kernel 1: three 1x1-conv projections, one bf16 MFMA GEMM.
// v4: ALL 64 per-lane x loads issued in the prologue (one ~900cyc HBM
// latency exposure instead of 8 partially-hidden ones).  512-thr blocks,
// double-buffered weight slices, theta pre-scaled by LOG2E.
// (byte-identical to the 187.7us verified kernel)
// ---------------------------------------------------------------------------
__global__ __launch_bounds__(512, 4) void proj_kernel(
    const float* __restrict__ x,
    const float* __restrict__ wg, const float* __restrict__ bg,
    const float* __restrict__ wt, const float* __restrict__ bt,
    const float* __restrict__ wp, const float* __restrict__ bp,
    unsigned short* __restrict__ gws,   // [B][CI][N]
    unsigned short* __restrict__ tws,   // [B][N][CI]  (theta, pre-scaled LOG2E)
    unsigned short* __restrict__ pws)   // [B][N][CI]
{
    constexpr int WS = 40;   // weight row stride (shorts)
    constexpr int GS = 72;   // transpose row stride
    __shared__ __align__(16) unsigned short wsl[2][192 * WS];
    __shared__ __align__(16) unsigned short gt[64 * GS];

    const int t    = threadIdx.x;
    const int lane = t & 63;
    const int w    = t >> 6;        // 0..7
    const int nf   = w >> 1;        // n-fragment group 0..3
    const int oh   = w & 1;         // oc-half 0..1
    const int l15  = lane & 15;
    const int quad = lane >> 4;
    const int n0   = blockIdx.x * 64;
    const int b    = blockIdx.y;

    floatx4 acc[6];
#pragma unroll
    for (int i = 0; i < 6; ++i) { floatx4 z = {0.f, 0.f, 0.f, 0.f}; acc[i] = z; }

    const int nA = n0 + nf * 16 + l15;
    const float* xbase = x + (size_t)b * C_ * N_ + nA;

    // ALL x loads upfront: 64 dwords/lane, independent -> deep MLP
    float xv[64];
#pragma unroll
    for (int kk = 0; kk < 8; ++kk)
#pragma unroll
        for (int j = 0; j < 8; ++j)
            xv[kk * 8 + j] = xbase[(size_t)(kk * 32 + quad * 8 + j) * N_];

    // stage weight slice 0 into buf 0 (rows 64..127 = theta: scale by LOG2E)
#pragma unroll
    for (int it = 0; it < 3; ++it) {
        int u = t + it * 512;                 // 0..1535
        int row = u >> 3, c4 = u & 7;
        const float* src = (row < 64)  ? (wg + row * C_)
                         : (row < 128) ? (wt + (row - 64) * C_)
                                       : (wp + (row - 128) * C_);
        const float sc = (row >= 64 && row < 128) ? LOG2E : 1.0f;
        float4 v = *(const float4*)(src + c4 * 4);
        uint2 uu = { pk2(v.x * sc, v.y * sc), pk2(v.z * sc, v.w * sc) };
        *(uint2*)&wsl[0][row * WS + c4 * 4] = uu;
    }
    __syncthreads();

    for (int kk = 0; kk < 8; ++kk) {
        uint4 au = { pk2(xv[kk * 8 + 0], xv[kk * 8 + 1]),
                     pk2(xv[kk * 8 + 2], xv[kk * 8 + 3]),
                     pk2(xv[kk * 8 + 4], xv[kk * 8 + 5]),
                     pk2(xv[kk * 8 + 6], xv[kk * 8 + 7]) };
        short8 af = __builtin_bit_cast(short8, au);

        if (kk < 7) {
#pragma unroll
            for (int it = 0; it < 3; ++it) {
                int u = t + it * 512;
                int row = u >> 3, c4 = u & 7;
                const float* src = (row < 64)  ? (wg + row * C_)
                                 : (row < 128) ? (wt + (row - 64) * C_)
                                               : (wp + (row - 128) * C_);
                const float sc = (row >= 64 && row < 128) ? LOG2E : 1.0f;
                float4 v = *(const float4*)(src + (kk + 1) * 32 + c4 * 4);
                uint2 uu = { pk2(v.x * sc, v.y * sc), pk2(v.z * sc, v.w * sc) };
                *(uint2*)&wsl[(kk + 1) & 1][row * WS + c4 * 4] = uu;
            }
        }

#pragma unroll
        for (int oti = 0; oti < 6; ++oti) {
            const int ot = oh * 6 + oti;
            short8 bf = *(const short8*)&wsl[kk & 1][(ot * 16 + l15) * WS + quad * 8];
            acc[oti] = mfma32(af, bf, acc[oti]);
        }
        __syncthreads();
    }

    // epilogue: bias + stores
#pragma unroll
    for (int oti = 0; oti < 6; ++oti) {
        const int ot = oh * 6 + oti;
        const int oc = ot * 16 + l15;
        const float bias = (ot < 4) ? bg[oc]
                         : (ot < 8) ? bt[oc - 64] * LOG2E
                                    : bp[oc - 128];
        if (ot < 4) {
#pragma unroll
            for (int r = 0; r < 4; ++r)
                gt[oc * GS + nf * 16 + quad * 4 + r] = f2bf(acc[oti][r] + bias);
        } else {
            unsigned short* dst = (ot < 8) ? tws : pws;
            const int ci = (ot < 8) ? (oc - 64) : (oc - 128);
#pragma unroll
            for (int r = 0; r < 4; ++r) {
                int n = n0 + nf * 16 + quad * 4 + r;
                dst[((size_t)b * N_ + n) * CI_ + ci] = f2bf(acc[oti][r] + bias);
            }
        }
    }
    __syncthreads();
    // coalesced g store: 4096 shorts = 512 uint4, one per thread
    {
        int ci = t >> 3, n8 = t & 7;
        uint4 v = *(const uint4*)&gt[ci * GS + n8 * 8];
        *(uint4*)(gws + ((size_t)b * CI_ + ci) * N_ + n0 + n8 * 8) = v;
    }
}

// ---------------------------------------------------------------------------
// Kernel 2: flash attention v5 (the 187.7us VERIFIED kernel, byte-identical)
// + ONE delta: s_setprio(1)/(0) around the PV mfma16 cluster (T5, m191:
// +4-7% attn; uniform scalar priority hint, zero correctness surface).
// Purpose this round: re-establish a green base after v6-v9 failures and
// validate the environment; if this fails, v5 itself no longer passes and
// the environment is indicted.
// ---------------------------------------------------------------------------
__global__ __launch_bounds__(256, 4) void attn_kernel(
    const unsigned short* __restrict__ gws,  // V^T [B][CI][N]
    const unsigned short* __restrict__ tws,  // Q   [B][N][CI] (LOG2E-scaled)
    const unsigned short* __restrict__ pws,  // K   [B][N][CI]
    unsigned short* __restrict__ Opart,      // [KSPLIT][B][N][CI] bf16
    float* __restrict__ lpart)               // [KSPLIT][B][N]
{
    constexpr int LDW = 72;
    __shared__ __align__(16) unsigned short Vs[2][64 * LDW];

    const int t    = threadIdx.x;
    const int lane = t & 63;
    const int w    = t >> 6;
    const int l15  = lane & 15;
    const int quad = lane >> 4;
    const int b    = blockIdx.x;
    const int q0   = blockIdx.y * 128;
    const int sp   = blockIdx.z;

    const int srow = t >> 3;   // 0..31 (ci)
    const int sc8  = t & 7;    // 16B column

    const unsigned short* kslice = pws + ((size_t)b * N_ + sp * (N_ / KSPLIT)) * CI_;
    const unsigned short* vbase  =
        gws + ((size_t)b * CI_ + srow) * N_ + sp * (N_ / KSPLIT) + sc8 * 8;

    // Q fragments (loop-invariant), 2 q-groups of 16 rows
    short8 qf[2][2];
#pragma unroll
    for (int qg = 0; qg < 2; ++qg) {
        const unsigned short* qrow =
            tws + ((size_t)b * N_ + q0 + w * 32 + qg * 16 + l15) * CI_;
        qf[qg][0] = *(const short8*)(qrow + quad * 8);
        qf[qg][1] = *(const short8*)(qrow + 32 + quad * 8);
    }

    // prologue: V tile 0 -> buf 0
    {
        uint4 v0 = *(const uint4*)(vbase);
        uint4 v1 = *(const uint4*)(vbase + 32 * N_);
        *(uint4*)&Vs[0][srow * LDW + sc8 * 8]        = v0;
        *(uint4*)&Vs[0][(srow + 32) * LDW + sc8 * 8] = v1;
    }
    __syncthreads();

    sh4 ones4;
#pragma unroll
    for (int j = 0; j < 4; ++j) ones4[j] = (short)0x3F80;   // bf16 1.0

    floatx4 Oacc[2][4], lacc[2];
    { floatx4 z = {0.f, 0.f, 0.f, 0.f};
      lacc[0] = z; lacc[1] = z;
#pragma unroll
      for (int qg = 0; qg < 2; ++qg)
#pragma unroll
          for (int f = 0; f < 4; ++f) Oacc[qg][f] = z; }

    for (int j = 0; j < KTILES; ++j) {
        const int p  = j & 1;
        const int jn = (j + 1) & (KTILES - 1);

        // batch-issue: next V tile + ALL 8 K fragments of this tile
        uint4 pv0 = *(const uint4*)(vbase + jn * 64);
        uint4 pv1 = *(const uint4*)(vbase + 32 * N_ + jn * 64);

        const unsigned short* kt = kslice + (size_t)j * 64 * CI_;
        short8 ka[4][2];
#pragma unroll
        for (int f = 0; f < 4; ++f) {
            ka[f][0] = *(const short8*)(kt + (f * 16 + l15) * CI_ + quad * 8);
            ka[f][1] = *(const short8*)(kt + (f * 16 + l15) * CI_ + 32 + quad * 8);
        }

#pragma unroll
        for (int f = 0; f < 4; ++f) {
            sh4 pfr[2];
#pragma unroll
            for (int qg = 0; qg < 2; ++qg) {
                floatx4 s = {0.f, 0.f, 0.f, 0.f};
                s = mfma32(ka[f][0], qf[qg][0], s);
                s = mfma32(ka[f][1], qf[qg][1], s);
                uint2 uu = { pk2(__builtin_amdgcn_exp2f(s[0]),
                                 __builtin_amdgcn_exp2f(s[1])),
                             pk2(__builtin_amdgcn_exp2f(s[2]),
                                 __builtin_amdgcn_exp2f(s[3])) };
                pfr[qg] = __builtin_bit_cast(sh4, uu);
                lacc[qg] = mfma16(pfr[qg], ones4, lacc[qg]);
            }
            __builtin_amdgcn_s_setprio(1);
#pragma unroll
            for (int fc = 0; fc < 4; ++fc) {
                sh4 vb = *(const sh4*)&Vs[p][(fc * 16 + l15) * LDW + f * 16 + quad * 4];
#pragma unroll
                for (int qg = 0; qg < 2; ++qg)
                    Oacc[qg][fc] = mfma16(pfr[qg], vb, Oacc[qg][fc]);
            }
            __builtin_amdgcn_s_setprio(0);
        }

        // commit V prefetch to alternate buffer
        *(uint4*)&Vs[1 - p][srow * LDW + sc8 * 8]        = pv0;
        *(uint4*)&Vs[1 - p][(srow + 32) * LDW + sc8 * 8] = pv1;

        __syncthreads();
    }

    // epilogue: unnormalized partials, bf16
#pragma unroll
    for (int qg = 0; qg < 2; ++qg) {
#pragma unroll
        for (int r = 0; r < 4; ++r) {
            int row = q0 + w * 32 + qg * 16 + quad * 4 + r;
            size_t obase = ((size_t)(sp * B_ + b) * N_ + row) * CI_;
#pragma unroll
            for (int fc = 0; fc < 4; ++fc)
                Opart[obase + fc * 16 + l15] = f2bf(Oacc[qg][fc][r]);
            if (l15 == 0)
                lpart[(size_t)(sp * B_ + b) * N_ + row] = lacc[qg][r];
        }
    }
}

// ---------------------------------------------------------------------------
// Kernel 3: combine KSPLIT bf16 partials + w conv + bias + residual.
// (byte-identical to the 187.7us verified kernel)
// ---------------------------------------------------------------------------
__global__ __launch_bounds__(256, 4) void out_kernel(
    const unsigned short* __restrict__ Opart, // [KSPLIT][B][N][CI] bf16
    const float* __restrict__ lpart,          // [KSPLIT][B][N]
    const float* __restrict__ ww,             // [C][CI]
    const float* __restrict__ wb,             // [C]
    const float* __restrict__ x,              // [B][C][N]
    float* __restrict__ out)                  // [B][C][N]
{
    constexpr int WS = 72;   // weight row stride (shorts)
    constexpr int TS = 66;   // transpose row stride (floats)
    __shared__ __align__(16) char smem[128 * TS * 4];   // 33792 B, aliased
    unsigned short* wws = (unsigned short*)smem;
    float*          T   = (float*)smem;

    const int t    = threadIdx.x;
    const int lane = t & 63;
    const int w    = t >> 6;
    const int l15  = lane & 15;
    const int quad = lane >> 4;
    const int n0   = blockIdx.x * 64;
    const int b    = blockIdx.y;
    const int ch   = blockIdx.z;             // c-half: rows ch*128..+128

    // phase 1: stage this half's W_w rows -> bf16 LDS
#pragma unroll
    for (int it = 0; it < 8; ++it) {
        int u = t + it * 256;                // 0..2047 float4 units
        int row = u >> 4, c4 = u & 15;
        float4 v = *(const float4*)(ww + (ch * 128 + row) * CI_ + c4 * 4);
        uint2 uu = { pk2(v.x, v.y), pk2(v.z, v.w) };
        *(uint2*)&wws[row * WS + c4 * 4] = uu;
    }
    __syncthreads();

    floatx4 acc[8];
#pragma unroll
    for (int ot = 0; ot < 8; ++ot) { floatx4 z = {0.f, 0.f, 0.f, 0.f}; acc[ot] = z; }

    const int nB = n0 + w * 16 + l15;
    float lsum = 0.f;
#pragma unroll
    for (int sp = 0; sp < KSPLIT; ++sp)
        lsum += lpart[(size_t)(sp * B_ + b) * N_ + nB];
    const float inv = 1.f / lsum;

#pragma unroll
    for (int ks = 0; ks < 2; ++ks) {
        float ysum[8] = {0.f, 0.f, 0.f, 0.f, 0.f, 0.f, 0.f, 0.f};
#pragma unroll
        for (int sp = 0; sp < KSPLIT; ++sp) {
            short8 ov = *(const short8*)(Opart +
                ((size_t)(sp * B_ + b) * N_ + nB) * CI_ + ks * 32 + quad * 8);
#pragma unroll
            for (int e = 0; e < 8; ++e)
                ysum[e] += bf2f((unsigned short)ov[e]);
        }
        uint4 bu = { pk2(ysum[0] * inv, ysum[1] * inv),
                     pk2(ysum[2] * inv, ysum[3] * inv),
                     pk2(ysum[4] * inv, ysum[5] * inv),
                     pk2(ysum[6] * inv, ysum[7] * inv) };
        short8 bfrag = __builtin_bit_cast(short8, bu);
#pragma unroll
        for (int ot = 0; ot < 8; ++ot) {
            short8 afrag = *(const short8*)&wws[(ot * 16 + l15) * WS + ks * 32 + quad * 8];
            acc[ot] = mfma32(afrag, bfrag, acc[ot]);
        }
    }
    __syncthreads();   // done reading wws; smem becomes T

    // phase 2: acc + bias -> T[c][n] fp32
#pragma unroll
    for (int ot = 0; ot < 8; ++ot) {
#pragma unroll
        for (int r = 0; r < 4; ++r) {
            int cr = ot * 16 + quad * 4 + r;
            T[cr * TS + w * 16 + l15] = acc[ot][r] + wb[ch * 128 + cr];
        }
    }
    __syncthreads();

    // phase 3: coalesced float4 residual + store (256B segments per 16 lanes)
    const int c0 = t >> 4;       // 0..15
    const int nq = t & 15;       // float4 column
#pragma unroll
    for (int i = 0; i < 8; ++i) {
        int cr = c0 + 16 * i;    // 0..127
        float4 tv = *(const float4*)&T[cr * TS + nq * 4];
        size_t idx = ((size_t)b * C_ + ch * 128 + cr) * N_ + n0 + nq * 4;
        float4 xv = *(const float4*)(x + idx);
        float4 ov = { tv.x + xv.x, tv.y + xv.y, tv.z + xv.z, tv.w + xv.w };
        *(float4*)(out + idx) = ov;
    }
}

extern "C" void kernel_launch(void* const* d_in, const int* in_sizes, int n_in,
                              void* d_out, int out_size, void* d_ws, size_t ws_size,
                              hipStream_t stream) {
    const float* x  = (const float*)d_in[0];
    const float* gw = (const float*)d_in[1];
    const float* gb = (const float*)d_in[2];
    const float* tw = (const float*)d_in[3];
    const float* tb = (const float*)d_in[4];
    const float* pw = (const float*)d_in[5];
    const float* pb = (const float*)d_in[6];
    const float* ww = (const float*)d_in[7];
    const float* wb = (const float*)d_in[8];
    float* out = (float*)d_out;

    char* ws = (char*)d_ws;
    unsigned short* gws   = (unsigned short*)(ws);              // 4MB   V^T bf16
    unsigned short* tws   = (unsigned short*)(ws + (4  << 20)); // 4MB   Q bf16
    unsigned short* pws   = (unsigned short*)(ws + (8  << 20)); // 4MB   K bf16
    unsigned short* Opart = (unsigned short*)(ws + (12 << 20)); // 16MB  O partials bf16
    float*          lpart = (float*)        (ws + (28 << 20));  // 512KB l partials

    proj_kernel<<<dim3(64, 8), 512, 0, stream>>>(x, gw, gb, tw, tb, pw, pb, gws, tws, pws);
    attn_kernel<<<dim3(8, 32, KSPLIT), 256, 0, stream>>>(gws, tws, pws, Opart, lpart);
    out_kernel<<<dim3(64, 8, 2), 256, 0, stream>>>(Opart, lpart, ww, wb, x, out);
}